// Round 1
// baseline (194.071 us; speedup 1.0000x reference)
//
#include <hip/hip_runtime.h>

typedef unsigned long long u64;

#define G 512
#define T 128
#define P 256
#define B 512

// ---------------- workspace layout ----------------
// pv_ws   : B*4 u64      =  16 KB   (packed param_vals bitmasks)
// rows_ws : G*T*8 u64    =   4 MB   ([g*T+t][0..3]=psi words, [4..7]=phi words)
// codes_ws: G*T u32      = 256 KB   (bit0 = psi_const, bit1 = phi_const)
#define PV_OFF    0
#define ROWS_OFF  16384
#define CODES_OFF (ROWS_OFF + (size_t)G * T * 8 * 8)
#define WS_NEEDED (CODES_OFF + (size_t)G * T * 4)

// Bit layout everywhere: word j (j=0..3), bit L  <->  p = 4*L + j.
// Identical permutation on matrices and param_vals, so AND-parity is preserved.

// ---------------- pack pass ----------------
// Task list: 0..65535 = psi rows, 65536..131071 = phi rows, then 512 pv rows.
// One wave per row: 64 lanes x float4 = full 256-float row -> 4 ballots -> 32 B.
#define ROWS_TOTAL (G * T * 2)          // 131072
#define TASKS      (ROWS_TOTAL + B)     // 131584
#define TPW        16                   // tasks per wave
#define PACK_BLOCKS (TASKS / (TPW * 4)) // 2056 blocks x 4 waves, exact fit

__global__ __launch_bounds__(256) void pack_all_kernel(
    const int*   __restrict__ psi_const,
    const float* __restrict__ psi_params,
    const int*   __restrict__ phi_const,
    const float* __restrict__ phi_params,
    const float* __restrict__ pv,
    u64*         __restrict__ rows_ws,
    unsigned*    __restrict__ codes_ws,
    u64*         __restrict__ pv_ws)
{
    // const-bit codes: one thread per (g,t), coalesced
    int gtid = blockIdx.x * 256 + threadIdx.x;
    if (gtid < G * T) {
        unsigned pc = ((unsigned)psi_const[gtid]) & 1u;
        unsigned qc = ((unsigned)phi_const[gtid]) & 1u;
        codes_ws[gtid] = pc | (qc << 1);
    }

    const int lane = threadIdx.x & 63;
    const int wv   = (blockIdx.x << 2) | (threadIdx.x >> 6);
    const int base = wv * TPW;

    for (int i = 0; i < TPW; ++i) {
        int task = base + i;                 // wave-uniform
        const float* src;
        u64* dst;
        if (task < ROWS_TOTAL) {
            int mat = task >> 16;            // 0 = psi, 1 = phi  (G*T = 1<<16)
            int idx = task & (G * T - 1);    // g*T + t
            src = (mat ? phi_params : psi_params) + (size_t)idx * P;
            dst = rows_ws + (size_t)idx * 8 + mat * 4;
        } else {
            int b = task - ROWS_TOTAL;
            src = pv + (size_t)b * P;
            dst = pv_ws + (size_t)b * 4;
        }
        float4 f = ((const float4*)src)[lane];
        u64 w0 = __ballot(f.x != 0.0f);
        u64 w1 = __ballot(f.y != 0.0f);
        u64 w2 = __ballot(f.z != 0.0f);
        u64 w3 = __ballot(f.w != 0.0f);
        if (lane == 0) {
            dst[0] = w0; dst[1] = w1; dst[2] = w2; dst[3] = w3;
        }
    }
}

// ---------------- compute pass (LDS-free) ----------------
// 1024 blocks x 256 threads: block = (g, half of b-range), thread = one b.
// Mask/code addresses are block-uniform -> scalar loads (SGPR) feeding
// v_and_b32 v,s,v; per t: 16 AND + 12 XOR + 2x popcll + 4 combine ops.
__global__ __launch_bounds__(256) void pi_main2_kernel(
    const u64*      __restrict__ rows,
    const unsigned* __restrict__ codes,
    const u64*      __restrict__ pv,
    float4*         __restrict__ out)
{
    const int g = blockIdx.x >> 1;
    const int b = ((blockIdx.x & 1) << 8) | threadIdx.x;

    const u64* v = pv + (size_t)b * 4;
    u64 v0 = v[0], v1 = v[1], v2 = v[2], v3 = v[3];

    const u64*      Rg = rows  + (size_t)g * (T * 8);
    const unsigned* Cg = codes + g * T;

    unsigned e = 0;
    #pragma unroll 4
    for (int t = 0; t < T; ++t) {
        const u64* r = Rg + t * 8;           // uniform address
        u64 ma = (r[0] & v0) ^ (r[1] & v1) ^ (r[2] & v2) ^ (r[3] & v3);
        u64 mb = (r[4] & v0) ^ (r[5] & v1) ^ (r[6] & v2) ^ (r[7] & v3);
        unsigned c = Cg[t];
        // bit0 of ((popc_a ^ pc) & (popc_b ^ qc)); high garbage masked at end
        e ^= (((unsigned)__popcll(ma) ^ c) & ((unsigned)__popcll(mb) ^ (c >> 1)));
    }
    e &= 1u;

    float s = 1.0f - 2.0f * (float)e;        // (-1)^e
    out[(size_t)b * G + g] = make_float4(s, 0.0f, 0.0f, 0.0f);
}

// ---------------- fallback path (previous verified kernels) ----------------
struct __align__(16) U64x2 { u64 x, y; };

__global__ __launch_bounds__(256) void pack_pv_kernel(
    const float* __restrict__ pv, u64* __restrict__ out)
{
    int lane = threadIdx.x & 63;
    int wave = threadIdx.x >> 6;
    int row  = blockIdx.x * 4 + wave;
    const float4* src = (const float4*)(pv + (size_t)row * P);
    float4 f = src[lane];
    u64 w0 = __ballot(f.x != 0.0f);
    u64 w1 = __ballot(f.y != 0.0f);
    u64 w2 = __ballot(f.z != 0.0f);
    u64 w3 = __ballot(f.w != 0.0f);
    if (lane == 0) {
        out[row * 4 + 0] = w0;
        out[row * 4 + 1] = w1;
        out[row * 4 + 2] = w2;
        out[row * 4 + 3] = w3;
    }
}

__global__ __launch_bounds__(512) void pi_main_kernel(
    const int*   __restrict__ psi_const,
    const float* __restrict__ psi_params,
    const int*   __restrict__ phi_const,
    const float* __restrict__ phi_params,
    const u64*   __restrict__ pv,
    float4*      __restrict__ out)
{
    __shared__ __align__(16) u64 rows[T * 8];
    __shared__ unsigned code_sm[T];

    const int g    = blockIdx.x;
    const int tid  = threadIdx.x;
    const int lane = tid & 63;
    const int wave = tid >> 6;

    if (tid < T) {
        unsigned pc = ((unsigned)psi_const[g * T + tid]) & 1u;
        unsigned qc = ((unsigned)phi_const[g * T + tid]) & 1u;
        code_sm[tid] = pc | (qc << 1);
    }

    for (int i = 0; i < 32; ++i) {
        int r = wave * 32 + i;
        int t = r & (T - 1);
        const float* mat = (r < T) ? psi_params : phi_params;
        int off = (r < T) ? 0 : 4;
        const float4* src = (const float4*)(mat + ((size_t)g * T + t) * P);
        float4 f = src[lane];
        u64 w0 = __ballot(f.x != 0.0f);
        u64 w1 = __ballot(f.y != 0.0f);
        u64 w2 = __ballot(f.z != 0.0f);
        u64 w3 = __ballot(f.w != 0.0f);
        if (lane == 0) {
            U64x2* d = (U64x2*)&rows[t * 8 + off];
            U64x2 a; a.x = w0; a.y = w1;
            U64x2 c; c.x = w2; c.y = w3;
            d[0] = a;
            d[1] = c;
        }
    }
    __syncthreads();

    const int b = tid;
    const u64* v = pv + (size_t)b * 4;
    u64 v0 = v[0], v1 = v[1], v2 = v[2], v3 = v[3];

    unsigned e = 0;
    #pragma unroll 8
    for (int t = 0; t < T; ++t) {
        const U64x2* row = (const U64x2*)&rows[t * 8];
        U64x2 p0 = row[0], p1 = row[1], q0 = row[2], q1 = row[3];
        u64 ma = (p0.x & v0) ^ (p0.y & v1) ^ (p1.x & v2) ^ (p1.y & v3);
        u64 mb = (q0.x & v0) ^ (q0.y & v1) ^ (q1.x & v2) ^ (q1.y & v3);
        unsigned c = code_sm[t];
        e ^= (((unsigned)__popcll(ma) ^ c) & ((unsigned)__popcll(mb) ^ (c >> 1)));
    }
    e &= 1u;

    float s = 1.0f - 2.0f * (float)e;
    out[(size_t)b * G + g] = make_float4(s, 0.0f, 0.0f, 0.0f);
}

// ---------------- launch ----------------
extern "C" void kernel_launch(void* const* d_in, const int* in_sizes, int n_in,
                              void* d_out, int out_size, void* d_ws, size_t ws_size,
                              hipStream_t stream) {
    const int*   psi_const  = (const int*)  d_in[0];
    const float* psi_params = (const float*)d_in[1];
    const int*   phi_const  = (const int*)  d_in[2];
    const float* phi_params = (const float*)d_in[3];
    const float* param_vals = (const float*)d_in[4];

    if (ws_size >= WS_NEEDED) {
        u64*      pv_ws    = (u64*)((char*)d_ws + PV_OFF);
        u64*      rows_ws  = (u64*)((char*)d_ws + ROWS_OFF);
        unsigned* codes_ws = (unsigned*)((char*)d_ws + CODES_OFF);

        pack_all_kernel<<<PACK_BLOCKS, 256, 0, stream>>>(
            psi_const, psi_params, phi_const, phi_params, param_vals,
            rows_ws, codes_ws, pv_ws);
        pi_main2_kernel<<<G * 2, 256, 0, stream>>>(
            rows_ws, codes_ws, pv_ws, (float4*)d_out);
    } else {
        // previous verified path (16 KB workspace)
        u64* pv_packed = (u64*)d_ws;
        pack_pv_kernel<<<B / 4, 256, 0, stream>>>(param_vals, pv_packed);
        pi_main_kernel<<<G, 512, 0, stream>>>(psi_const, psi_params,
                                              phi_const, phi_params,
                                              pv_packed, (float4*)d_out);
    }
}

// Round 2
// 188.348 us; speedup vs baseline: 1.0304x; 1.0304x over previous
//
#include <hip/hip_runtime.h>

typedef unsigned long long u64;

#define G 512
#define T 128
#define P 256
#define B 512

// ---------------- workspace layout ----------------
// pv_ws   : B*4 u64      =  16 KB   (packed param_vals bitmasks)
// rows_ws : G*T*8 u64    =   4 MB   ([g*T+t][0..3]=psi words, [4..7]=phi words)
// codes_ws: G*T u32      = 256 KB   (bit0 = psi_const, bit1 = phi_const)
#define PV_OFF    0
#define ROWS_OFF  16384
#define CODES_OFF (ROWS_OFF + (size_t)G * T * 8 * 8)
#define WS_NEEDED (CODES_OFF + (size_t)G * T * 4)

// Bit layout everywhere: word j (j=0..3), bit L  <->  p = 4*L + j.
// Identical permutation on matrices and param_vals, so AND-parity is preserved.

#define ROWS_TOTAL (G * T * 2)              // 131072
#define TPW        8                        // rows per wave, batch-loaded
#define ROW_BLOCKS (ROWS_TOTAL / (TPW * 4)) // 4096 blocks x 4 waves
#define PV_BLOCKS  (B / (TPW * 4))          // 16
#define PACK_BLOCKS (ROW_BLOCKS + PV_BLOCKS)

// ---------------- pack pass ----------------
// Branch-free inner loop: region (psi/phi/pv) resolved per-wave OUTSIDE the
// loop (8-row batches never straddle the 65536 boundary). All 8 float4 loads
// issued before any ballot -> 8 loads in flight per wave -> latency hidden.
__global__ __launch_bounds__(256) void pack_all_kernel(
    const int*   __restrict__ psi_const,
    const float* __restrict__ psi_params,
    const int*   __restrict__ phi_const,
    const float* __restrict__ phi_params,
    const float* __restrict__ pv,
    u64*         __restrict__ rows_ws,
    unsigned*    __restrict__ codes_ws,
    u64*         __restrict__ pv_ws)
{
    // const-bit codes: one thread per (g,t), coalesced (blocks 0..255 cover it)
    int gtid = blockIdx.x * 256 + threadIdx.x;
    if (gtid < G * T) {
        unsigned pc = ((unsigned)psi_const[gtid]) & 1u;
        unsigned qc = ((unsigned)phi_const[gtid]) & 1u;
        codes_ws[gtid] = pc | (qc << 1);
    }

    const int lane = threadIdx.x & 63;
    const int wvin = threadIdx.x >> 6;

    const float* srcb;
    u64*         dstb;
    size_t       dst_stride;   // u64s between consecutive rows at dst
    if (blockIdx.x < ROW_BLOCKS) {
        int base = (blockIdx.x * 4 + wvin) * TPW;   // wave-uniform
        int mat  = base >> 16;                      // 0 = psi, 1 = phi
        int idx  = base & (G * T - 1);              // g*T + t
        srcb = (mat ? phi_params : psi_params) + (size_t)idx * P;
        dstb = rows_ws + (size_t)idx * 8 + mat * 4;
        dst_stride = 8;
    } else {
        int brow = ((blockIdx.x - ROW_BLOCKS) * 4 + wvin) * TPW;
        srcb = pv + (size_t)brow * P;
        dstb = pv_ws + (size_t)brow * 4;
        dst_stride = 4;
    }

    const float4* src = (const float4*)srcb;
    float4 f[TPW];
    #pragma unroll
    for (int i = 0; i < TPW; ++i)
        f[i] = src[i * (P / 4) + lane];

    u64 w[TPW][4];
    #pragma unroll
    for (int i = 0; i < TPW; ++i) {
        w[i][0] = __ballot(f[i].x != 0.0f);
        w[i][1] = __ballot(f[i].y != 0.0f);
        w[i][2] = __ballot(f[i].z != 0.0f);
        w[i][3] = __ballot(f[i].w != 0.0f);
    }

    if (lane == 0) {
        #pragma unroll
        for (int i = 0; i < TPW; ++i) {
            ulonglong2* d = (ulonglong2*)(dstb + (size_t)i * dst_stride);
            d[0] = make_ulonglong2(w[i][0], w[i][1]);
            d[1] = make_ulonglong2(w[i][2], w[i][3]);
        }
    }
}

// ---------------- compute pass (transposed, register-resident) ----------------
// Block = graph g, 512 threads (8 waves). Lane l owns terms t=l and t=l+64,
// whose packed rows live in 32 VGPRs (coalesced load, once per block).
// Loop over b: pv mask (32 B) hoisted to SGPRs via readfirstlane-uniform base;
// per-b 1-bit results for 32 consecutive b packed into one u32 per lane,
// then one 6-step XOR shuffle-reduce covers 32 outputs.
__global__ __launch_bounds__(512) void pi_trans_kernel(
    const u64*      __restrict__ rows,
    const unsigned* __restrict__ codes,
    const u64*      __restrict__ pv,
    float4*         __restrict__ out)
{
    const int g    = blockIdx.x;
    const int lane = threadIdx.x & 63;
    const int wv   = threadIdx.x >> 6;

    const u64* Rg = rows + (size_t)g * (T * 8);

    u64 ra[8], rb[8];   // [0..3]=psi words, [4..7]=phi words for t=lane, t=lane+64
    {
        const ulonglong2* p0 = (const ulonglong2*)(Rg + (size_t)lane * 8);
        const ulonglong2* p1 = (const ulonglong2*)(Rg + (size_t)(lane + 64) * 8);
        #pragma unroll
        for (int q = 0; q < 4; ++q) { ulonglong2 x = p0[q]; ra[2*q] = x.x; ra[2*q+1] = x.y; }
        #pragma unroll
        for (int q = 0; q < 4; ++q) { ulonglong2 x = p1[q]; rb[2*q] = x.x; rb[2*q+1] = x.y; }
    }
    unsigned ca = codes[g * T + lane];
    unsigned cb = codes[g * T + lane + 64];
    unsigned pa = ca & 1u, qa = (ca >> 1) & 1u;
    unsigned pb = cb & 1u, qb = (cb >> 1) & 1u;

    #pragma unroll
    for (int grp = 0; grp < 2; ++grp) {
        int b0  = wv * 64 + grp * 32;
        int b0u = __builtin_amdgcn_readfirstlane(b0);   // force SGPR base -> s_load
        const u64* vp = pv + (size_t)b0u * 4;

        unsigned acc = 0;
        #pragma unroll
        for (int i = 0; i < 32; ++i) {
            u64 v0 = vp[i * 4 + 0], v1 = vp[i * 4 + 1];
            u64 v2 = vp[i * 4 + 2], v3 = vp[i * 4 + 3];
            u64 m0 = (ra[0] & v0) ^ (ra[1] & v1) ^ (ra[2] & v2) ^ (ra[3] & v3);
            u64 m1 = (ra[4] & v0) ^ (ra[5] & v1) ^ (ra[6] & v2) ^ (ra[7] & v3);
            u64 m2 = (rb[0] & v0) ^ (rb[1] & v1) ^ (rb[2] & v2) ^ (rb[3] & v3);
            u64 m3 = (rb[4] & v0) ^ (rb[5] & v1) ^ (rb[6] & v2) ^ (rb[7] & v3);
            unsigned f0 = (unsigned)m0 ^ (unsigned)(m0 >> 32);
            unsigned f1 = (unsigned)m1 ^ (unsigned)(m1 >> 32);
            unsigned f2 = (unsigned)m2 ^ (unsigned)(m2 >> 32);
            unsigned f3 = (unsigned)m3 ^ (unsigned)(m3 >> 32);
            unsigned t01 = ((unsigned)__popc(f0) ^ pa) & ((unsigned)__popc(f1) ^ qa);
            unsigned t23 = ((unsigned)__popc(f2) ^ pb) & ((unsigned)__popc(f3) ^ qb);
            acc ^= ((t01 ^ t23) & 1u) << i;
        }

        unsigned red = acc;
        #pragma unroll
        for (int m = 1; m < 64; m <<= 1)
            red ^= __shfl_xor(red, m, 64);

        if (lane < 32) {
            int b = b0u + lane;
            float s = 1.0f - 2.0f * (float)((red >> lane) & 1u);
            out[(size_t)b * G + g] = make_float4(s, 0.0f, 0.0f, 0.0f);
        }
    }
}

// ---------------- fallback path (previous verified kernels) ----------------
struct __align__(16) U64x2 { u64 x, y; };

__global__ __launch_bounds__(256) void pack_pv_kernel(
    const float* __restrict__ pv, u64* __restrict__ out)
{
    int lane = threadIdx.x & 63;
    int wave = threadIdx.x >> 6;
    int row  = blockIdx.x * 4 + wave;
    const float4* src = (const float4*)(pv + (size_t)row * P);
    float4 f = src[lane];
    u64 w0 = __ballot(f.x != 0.0f);
    u64 w1 = __ballot(f.y != 0.0f);
    u64 w2 = __ballot(f.z != 0.0f);
    u64 w3 = __ballot(f.w != 0.0f);
    if (lane == 0) {
        out[row * 4 + 0] = w0;
        out[row * 4 + 1] = w1;
        out[row * 4 + 2] = w2;
        out[row * 4 + 3] = w3;
    }
}

__global__ __launch_bounds__(512) void pi_main_kernel(
    const int*   __restrict__ psi_const,
    const float* __restrict__ psi_params,
    const int*   __restrict__ phi_const,
    const float* __restrict__ phi_params,
    const u64*   __restrict__ pv,
    float4*      __restrict__ out)
{
    __shared__ __align__(16) u64 rows[T * 8];
    __shared__ unsigned code_sm[T];

    const int g    = blockIdx.x;
    const int tid  = threadIdx.x;
    const int lane = tid & 63;
    const int wave = tid >> 6;

    if (tid < T) {
        unsigned pc = ((unsigned)psi_const[g * T + tid]) & 1u;
        unsigned qc = ((unsigned)phi_const[g * T + tid]) & 1u;
        code_sm[tid] = pc | (qc << 1);
    }

    for (int i = 0; i < 32; ++i) {
        int r = wave * 32 + i;
        int t = r & (T - 1);
        const float* mat = (r < T) ? psi_params : phi_params;
        int off = (r < T) ? 0 : 4;
        const float4* src = (const float4*)(mat + ((size_t)g * T + t) * P);
        float4 f = src[lane];
        u64 w0 = __ballot(f.x != 0.0f);
        u64 w1 = __ballot(f.y != 0.0f);
        u64 w2 = __ballot(f.z != 0.0f);
        u64 w3 = __ballot(f.w != 0.0f);
        if (lane == 0) {
            U64x2* d = (U64x2*)&rows[t * 8 + off];
            U64x2 a; a.x = w0; a.y = w1;
            U64x2 c; c.x = w2; c.y = w3;
            d[0] = a;
            d[1] = c;
        }
    }
    __syncthreads();

    const int b = tid;
    const u64* v = pv + (size_t)b * 4;
    u64 v0 = v[0], v1 = v[1], v2 = v[2], v3 = v[3];

    unsigned e = 0;
    #pragma unroll 8
    for (int t = 0; t < T; ++t) {
        const U64x2* row = (const U64x2*)&rows[t * 8];
        U64x2 p0 = row[0], p1 = row[1], q0 = row[2], q1 = row[3];
        u64 ma = (p0.x & v0) ^ (p0.y & v1) ^ (p1.x & v2) ^ (p1.y & v3);
        u64 mb = (q0.x & v0) ^ (q0.y & v1) ^ (q1.x & v2) ^ (q1.y & v3);
        unsigned c = code_sm[t];
        e ^= (((unsigned)__popcll(ma) ^ c) & ((unsigned)__popcll(mb) ^ (c >> 1)));
    }
    e &= 1u;

    float s = 1.0f - 2.0f * (float)e;
    out[(size_t)b * G + g] = make_float4(s, 0.0f, 0.0f, 0.0f);
}

// ---------------- launch ----------------
extern "C" void kernel_launch(void* const* d_in, const int* in_sizes, int n_in,
                              void* d_out, int out_size, void* d_ws, size_t ws_size,
                              hipStream_t stream) {
    const int*   psi_const  = (const int*)  d_in[0];
    const float* psi_params = (const float*)d_in[1];
    const int*   phi_const  = (const int*)  d_in[2];
    const float* phi_params = (const float*)d_in[3];
    const float* param_vals = (const float*)d_in[4];

    if (ws_size >= WS_NEEDED) {
        u64*      pv_ws    = (u64*)((char*)d_ws + PV_OFF);
        u64*      rows_ws  = (u64*)((char*)d_ws + ROWS_OFF);
        unsigned* codes_ws = (unsigned*)((char*)d_ws + CODES_OFF);

        pack_all_kernel<<<PACK_BLOCKS, 256, 0, stream>>>(
            psi_const, psi_params, phi_const, phi_params, param_vals,
            rows_ws, codes_ws, pv_ws);
        pi_trans_kernel<<<G, 512, 0, stream>>>(
            rows_ws, codes_ws, pv_ws, (float4*)d_out);
    } else {
        // previous verified path (16 KB workspace)
        u64* pv_packed = (u64*)d_ws;
        pack_pv_kernel<<<B / 4, 256, 0, stream>>>(param_vals, pv_packed);
        pi_main_kernel<<<G, 512, 0, stream>>>(psi_const, psi_params,
                                              phi_const, phi_params,
                                              pv_packed, (float4*)d_out);
    }
}